// Round 6
// baseline (235.866 us; speedup 1.0000x reference)
//
#include <hip/hip_runtime.h>
#include <hip/hip_cooperative_groups.h>
#include <math.h>

namespace cg = cooperative_groups;

// Problem constants
#define BATCH 8
#define NVERT 8192
#define NPD   64
#define NCELL 4096             // 64*64 grid cells per batch
#define SPLITS 64              // blocks per batch
#define JPB   (NVERT / SPLITS) // 128 vertices per block
#define G     16               // vertices staged per round
#define ROUNDS (JPB / G)       // 8
#define SLICES 256             // per-batch partial slices (SPLITS * 4 waves)

#ifndef M_PI
#define M_PI 3.14159265358979323846
#endif

// ws layout (floats)
#define TOTPART_OFF  0         // totpart[2048]
#define PARAMS_OFF   2048      // scale[8]
#define PARTIALS_OFF 4096      // 2048 * 4096 floats = 33.5 MB

static __device__ __forceinline__ float fast_exp2(float x) {
#if __has_builtin(__builtin_amdgcn_exp2f)
    return __builtin_amdgcn_exp2f(x);
#else
    return exp2f(x);
#endif
}

// ---------------------------------------------------------------------------
// Fused kernel: sigma + separable KDE (+ optional grid.sync + finish).
// Grid = BATCH*SPLITS = 512 blocks x 256 threads (4 waves, 2 blocks/CU max
// demand -> all co-resident). Each WAVE owns a full 64x64 grid (8x8 cells
// per thread) for a disjoint 32-vertex subset.
// COOP=true : single dispatch, grid-wide sync, finish inline.
// COOP=false: writes partials/totpart/params; finish_kernel does phase 3.
// ---------------------------------------------------------------------------
template <bool COOP>
__global__ __launch_bounds__(256) void kde_fused(const float* __restrict__ T,
                                                 float* __restrict__ params,
                                                 float* __restrict__ totpart,
                                                 float* __restrict__ partials,
                                                 float* __restrict__ out) {
    const int b   = blockIdx.x >> 6;           // / SPLITS
    const int sp  = blockIdx.x & (SPLITS - 1);
    const int j0  = sp * JPB;
    const int tid = threadIdx.x;
    const int w    = tid >> 6;                 // wave id 0..3
    const int lane = tid & 63;

    __shared__ float  es[2][G][128];  // [buf][g][0..63]=ex row, [64..127]=ey row
    __shared__ float2 tj[JPB];        // this block's vertex slice
    __shared__ float  red[4][4];
    __shared__ float  red2[4][64];    // phase-3 per-wave cell sums
    __shared__ float  bcast[2];       // kexp2, scale

    // ---- phase 0: sigma over the full batch (redundant per block) ----
    const float4* T4 = reinterpret_cast<const float4*>(T + (size_t)b * NVERT * 2);
    float sx = 0.f, sx2 = 0.f, sy = 0.f, sy2 = 0.f;
    for (int q = tid; q < NVERT / 2; q += 256) {   // 2 vertices per float4
        float4 v = T4[q];
        sx += v.x + v.z;
        sy += v.y + v.w;
        sx2 += v.x * v.x + v.z * v.z;
        sy2 += v.y * v.y + v.w * v.w;
        int local = 2 * q - j0;                    // even when in range
        if ((unsigned)local < (unsigned)JPB)
            *reinterpret_cast<float4*>(&tj[local]) = v;
    }
    for (int off = 32; off; off >>= 1) {
        sx  += __shfl_down(sx,  off);  sx2 += __shfl_down(sx2, off);
        sy  += __shfl_down(sy,  off);  sy2 += __shfl_down(sy2, off);
    }
    if (lane == 0) { red[w][0] = sx; red[w][1] = sx2; red[w][2] = sy; red[w][3] = sy2; }
    __syncthreads();
    if (tid == 0) {
        double tsx = 0, tsx2 = 0, tsy = 0, tsy2 = 0;
        for (int i = 0; i < 4; ++i) {
            tsx += red[i][0]; tsx2 += red[i][1]; tsy += red[i][2]; tsy2 += red[i][3];
        }
        const double N = (double)NVERT;
        double varx = (tsx2 - tsx * tsx / N) / (N - 1.0);
        double vary = (tsy2 - tsy * tsy / N) / (N - 1.0);
        double sigma = 0.5 * (sqrt(varx) + sqrt(vary));
        const double BD = 1.0 / 63.0;
        if (sigma < BD) sigma = BD;
        const double C2 = pow(2.0, -13.0 / 3.0);   // C^2, C = NV^(-1/6)
        double s2 = sigma * sigma;
        bcast[0] = (float)(-0.5 / C2 / (s2 * 0.69314718055994530942)); // exp2 coeff
        bcast[1] = (float)(1.0 / (2.0 * M_PI * C2) / (s2 * N));        // CF*s^-2/NV
        if (sp == 0) params[b] = bcast[1];
    }
    __syncthreads();
    const float kexp2 = bcast[0];

    // ---- staging constants (round-invariant per thread) ----
    const int   c     = tid & 127;                 // column in es row
    const bool  isX   = (c < 64);
    const float xc    = (float)(c & 63) * (1.0f / 63.0f);
    const int   gbase = tid >> 7;                  // 0 or 1

#define STAGE(JG, BUF)                                                    \
    {                                                                     \
        _Pragma("unroll")                                                 \
        for (int r_ = 0; r_ < 8; ++r_) {                                  \
            int g = r_ * 2 + gbase;                                       \
            float2 t2 = tj[(JG) + g];                                     \
            float tv = isX ? t2.x : t2.y;                                 \
            float d = xc - tv;                                            \
            es[BUF][g][c] = fast_exp2(kexp2 * d * d);                     \
        }                                                                 \
    }

    // ---- phase 1: double-buffered separable outer-product, 1 barrier/round --
    const int tx = lane >> 3;   // x-block: rows tx*8..tx*8+7
    const int ty = lane & 7;    // y-block: cols ty*8..ty*8+7
    float acc[8][8];
#pragma unroll
    for (int i = 0; i < 8; ++i)
#pragma unroll
        for (int j = 0; j < 8; ++j) acc[i][j] = 0.0f;

    STAGE(0, 0);                                   // prologue: round 0 -> buf 0
    for (int r = 0; r < ROUNDS; ++r) {
        __syncthreads();                           // round r staged; buf r+1 free
        if (r + 1 < ROUNDS) STAGE((r + 1) * G, (r + 1) & 1);
        const float (*E)[128] = es[r & 1];
#pragma unroll
        for (int v = 0; v < 4; ++v) {
            const float* row = E[(w << 2) + v];
            float4 ex0 = *reinterpret_cast<const float4*>(&row[tx * 8]);
            float4 ex1 = *reinterpret_cast<const float4*>(&row[tx * 8 + 4]);
            float4 ey0 = *reinterpret_cast<const float4*>(&row[64 + ty * 8]);
            float4 ey1 = *reinterpret_cast<const float4*>(&row[64 + ty * 8 + 4]);
            float ex[8] = {ex0.x, ex0.y, ex0.z, ex0.w, ex1.x, ex1.y, ex1.z, ex1.w};
            float ey[8] = {ey0.x, ey0.y, ey0.z, ey0.w, ey1.x, ey1.y, ey1.z, ey1.w};
#pragma unroll
            for (int i = 0; i < 8; ++i)
#pragma unroll
                for (int j = 0; j < 8; ++j)
                    acc[i][j] = fmaf(ex[i], ey[j], acc[i][j]);
        }
    }

    // ---- phase 2: per-wave partial slice + per-wave total ----
    float* dst = partials + ((size_t)blockIdx.x * 4 + w) * NCELL;
    float tsum = 0.f;
#pragma unroll
    for (int i = 0; i < 8; ++i) {
        float4 lo = make_float4(acc[i][0], acc[i][1], acc[i][2], acc[i][3]);
        float4 hi = make_float4(acc[i][4], acc[i][5], acc[i][6], acc[i][7]);
        int rowoff = (tx * 8 + i) * 64 + ty * 8;   // ty fastest -> coalesced
        *reinterpret_cast<float4*>(&dst[rowoff])     = lo;
        *reinterpret_cast<float4*>(&dst[rowoff + 4]) = hi;
        tsum += ((acc[i][0] + acc[i][1]) + (acc[i][2] + acc[i][3]))
              + ((acc[i][4] + acc[i][5]) + (acc[i][6] + acc[i][7]));
    }
    for (int off = 32; off; off >>= 1) tsum += __shfl_down(tsum, off);
    if (lane == 0) totpart[(size_t)blockIdx.x * 4 + w] = tsum;

    if constexpr (COOP) {
        // ---- grid-wide barrier: partials + totals visible device-wide ----
        __threadfence();
        cg::this_grid().sync();

        // ---- phase 3: finish this block's 64-cell strip of batch b ----
        const float* pbase = partials + (size_t)b * SLICES * NCELL + sp * 64 + lane;
        float s0 = 0.f, s1 = 0.f;
#pragma unroll 8
        for (int k = 0; k < 64; k += 2) {          // 2 chains
            s0 += pbase[(size_t)(w + 4 * k)     * NCELL];
            s1 += pbase[(size_t)(w + 4 * k + 4) * NCELL];
        }
        red2[w][lane] = s0 + s1;

        float v = totpart[b * SLICES + tid];
        for (int off = 32; off; off >>= 1) v += __shfl_down(v, off);
        if (lane == 0) red[w][0] = v;
        __syncthreads();

        if (w == 0) {
            const float tot   = (red[0][0] + red[1][0]) + (red[2][0] + red[3][0]);
            const float scale = bcast[1];
            const float denom = fmaxf(tot * scale, 1e-5f);
            const float K = ((red2[0][lane] + red2[1][lane])
                           + (red2[2][lane] + red2[3][lane])) * scale;
            out[b * NCELL + sp * 64 + lane] = K / denom;
        }
    }
}

// ---------------------------------------------------------------------------
// Fallback finish: sum 256 slices/batch, totals from totpart, scale+normalize.
// Grid = BATCH*16 blocks x 256 threads (1 thread per cell).
// ---------------------------------------------------------------------------
__global__ __launch_bounds__(256) void finish_kernel(const float* __restrict__ partials,
                                                     const float* __restrict__ totpart,
                                                     const float* __restrict__ params,
                                                     float* __restrict__ out) {
    const int b    = blockIdx.x >> 4;
    const int cell = ((blockIdx.x & 15) << 8) + threadIdx.x;
    const float* p = partials + (size_t)b * SLICES * NCELL + cell;
    float s0 = 0.f, s1 = 0.f, s2 = 0.f, s3 = 0.f;
    for (int k = 0; k < SLICES; k += 4) {          // 4 chains to hide latency
        s0 += p[(size_t)(k + 0) * NCELL];
        s1 += p[(size_t)(k + 1) * NCELL];
        s2 += p[(size_t)(k + 2) * NCELL];
        s3 += p[(size_t)(k + 3) * NCELL];
    }
    float s = (s0 + s1) + (s2 + s3);

    __shared__ float r4[4];
    float v = totpart[b * SLICES + threadIdx.x];
    for (int off = 32; off; off >>= 1) v += __shfl_down(v, off);
    if ((threadIdx.x & 63) == 0) r4[threadIdx.x >> 6] = v;
    __syncthreads();
    const float tot = (r4[0] + r4[1]) + (r4[2] + r4[3]);

    const float scale = params[b];
    const float denom = fmaxf(tot * scale, 1e-5f);
    out[b * NCELL + cell] = (s * scale) / denom;
}

// ---------------------------------------------------------------------------
extern "C" void kernel_launch(void* const* d_in, const int* in_sizes, int n_in,
                              void* d_out, int out_size, void* d_ws, size_t ws_size,
                              hipStream_t stream) {
    const float* T = (const float*)d_in[0];   // [B, NV, 2] f32
    // d_in[1] (S) is a deterministic 64x64 meshgrid in [0,1]^2 — derived inline.

    float* ws       = (float*)d_ws;
    float* totpart  = ws + TOTPART_OFF;
    float* params   = ws + PARAMS_OFF;
    float* partials = ws + PARTIALS_OFF;
    float* out      = (float*)d_out;

    void* args[] = { (void*)&T, (void*)&params, (void*)&totpart,
                     (void*)&partials, (void*)&out };
    hipError_t err = hipLaunchCooperativeKernel((void*)kde_fused<true>,
                                                dim3(BATCH * SPLITS), dim3(256),
                                                args, 0, stream);
    if (err != hipSuccess) {
        // Deterministic fallback: 2-dispatch pipeline, identical math.
        kde_fused<false><<<BATCH * SPLITS, 256, 0, stream>>>(T, params, totpart,
                                                             partials, out);
        finish_kernel<<<BATCH * 16, 256, 0, stream>>>(partials, totpart, params, out);
    }
}

// Round 7
// 76.673 us; speedup vs baseline: 3.0763x; 3.0763x over previous
//
#include <hip/hip_runtime.h>
#include <math.h>

// Problem constants
#define BATCH 8
#define NVERT 8192
#define NPD   64
#define NCELL 4096             // 64*64 grid cells per batch
#define SPLITS 64              // blocks per batch
#define JPB   (NVERT / SPLITS) // 128 vertices per block
#define G     16               // vertices staged per round
#define ROUNDS (JPB / G)       // 8

#ifndef M_PI
#define M_PI 3.14159265358979323846
#endif

// ws layout (floats)
#define TOTPART_OFF  0         // totpart[512]
#define PARAMS_OFF   1024      // scale[8]
#define PARTIALS_OFF 4096      // 512 * 4096 floats = 8 MB

static __device__ __forceinline__ float fast_exp2(float x) {
#if __has_builtin(__builtin_amdgcn_exp2f)
    return __builtin_amdgcn_exp2f(x);
#else
    return exp2f(x);
#endif
}

// ---------------------------------------------------------------------------
// Kernel A: sigma + separable KDE + cross-wave LDS reduce -> block partial.
// Grid = BATCH*SPLITS = 512 blocks x 256 threads (4 waves, 2 blocks/CU).
// Each WAVE owns a full 64x64 grid (8x8 cells/thread) for a disjoint
// 32-vertex subset; per 16-vertex round: double-buffered es staging
// (2048 exp2, ONE barrier), 64 FMA/vertex/thread.
// Epilogue: waves 0/2 write gA/gB, waves 1/3 add, all waves sum gA+gB ->
// one 16 KB coalesced block partial + block total. partials = 8 MB total.
// ---------------------------------------------------------------------------
__global__ __launch_bounds__(256) void kde_kernel(const float* __restrict__ T,
                                                  float* __restrict__ params,
                                                  float* __restrict__ totpart,
                                                  float* __restrict__ partials) {
    const int b   = blockIdx.x >> 6;           // / SPLITS
    const int sp  = blockIdx.x & (SPLITS - 1);
    const int j0  = sp * JPB;
    const int tid = threadIdx.x;
    const int w    = tid >> 6;                 // wave id 0..3
    const int lane = tid & 63;

    __shared__ float  smem_es[2 * G * 128];   // 16 KB; aliased as gA in epilogue
    __shared__ float  gB[NCELL];              // 16 KB
    __shared__ float2 tj[JPB];                // this block's vertex slice
    __shared__ float  red[4][4];
    __shared__ float  bcast[2];               // kexp2, scale
    float* gA = smem_es;

    // ---- phase 0: sigma over the full batch (redundant per block) ----
    const float4* T4 = reinterpret_cast<const float4*>(T + (size_t)b * NVERT * 2);
    float sx = 0.f, sx2 = 0.f, sy = 0.f, sy2 = 0.f;
    for (int q = tid; q < NVERT / 2; q += 256) {   // 2 vertices per float4
        float4 v = T4[q];
        sx += v.x + v.z;
        sy += v.y + v.w;
        sx2 += v.x * v.x + v.z * v.z;
        sy2 += v.y * v.y + v.w * v.w;
        int local = 2 * q - j0;                    // even when in range
        if ((unsigned)local < (unsigned)JPB)
            *reinterpret_cast<float4*>(&tj[local]) = v;
    }
    for (int off = 32; off; off >>= 1) {
        sx  += __shfl_down(sx,  off);  sx2 += __shfl_down(sx2, off);
        sy  += __shfl_down(sy,  off);  sy2 += __shfl_down(sy2, off);
    }
    if (lane == 0) { red[w][0] = sx; red[w][1] = sx2; red[w][2] = sy; red[w][3] = sy2; }
    __syncthreads();
    if (tid == 0) {
        double tsx = 0, tsx2 = 0, tsy = 0, tsy2 = 0;
        for (int i = 0; i < 4; ++i) {
            tsx += red[i][0]; tsx2 += red[i][1]; tsy += red[i][2]; tsy2 += red[i][3];
        }
        const double N = (double)NVERT;
        double varx = (tsx2 - tsx * tsx / N) / (N - 1.0);
        double vary = (tsy2 - tsy * tsy / N) / (N - 1.0);
        double sigma = 0.5 * (sqrt(varx) + sqrt(vary));
        const double BD = 1.0 / 63.0;
        if (sigma < BD) sigma = BD;
        const double C2 = pow(2.0, -13.0 / 3.0);   // C^2, C = NV^(-1/6)
        double s2 = sigma * sigma;
        bcast[0] = (float)(-0.5 / C2 / (s2 * 0.69314718055994530942)); // exp2 coeff
        bcast[1] = (float)(1.0 / (2.0 * M_PI * C2) / (s2 * N));        // CF*s^-2/NV
        if (sp == 0) params[b] = bcast[1];
    }
    __syncthreads();
    const float kexp2 = bcast[0];

    // ---- staging constants (round-invariant per thread) ----
    const int   c     = tid & 127;                 // column in es row
    const bool  isX   = (c < 64);
    const float xc    = (float)(c & 63) * (1.0f / 63.0f);
    const int   gbase = tid >> 7;                  // 0 or 1

#define STAGE(JG, BUF)                                                    \
    {                                                                     \
        _Pragma("unroll")                                                 \
        for (int r_ = 0; r_ < 8; ++r_) {                                  \
            int g = r_ * 2 + gbase;                                       \
            float2 t2 = tj[(JG) + g];                                     \
            float tv = isX ? t2.x : t2.y;                                 \
            float d = xc - tv;                                            \
            smem_es[((BUF) * G + g) * 128 + c] = fast_exp2(kexp2 * d * d);\
        }                                                                 \
    }

    // ---- phase 1: double-buffered separable outer-product, 1 barrier/round --
    const int tx = lane >> 3;   // x-block: rows tx*8..tx*8+7
    const int ty = lane & 7;    // y-block: cols ty*8..ty*8+7
    float acc[8][8];
#pragma unroll
    for (int i = 0; i < 8; ++i)
#pragma unroll
        for (int j = 0; j < 8; ++j) acc[i][j] = 0.0f;

    STAGE(0, 0);                                   // prologue: round 0 -> buf 0
    for (int r = 0; r < ROUNDS; ++r) {
        __syncthreads();                           // round r staged; buf r+1 free
        if (r + 1 < ROUNDS) STAGE((r + 1) * G, (r + 1) & 1);
        const float* E = &smem_es[(r & 1) * G * 128];
#pragma unroll
        for (int v = 0; v < 4; ++v) {
            const float* row = &E[((w << 2) + v) * 128];
            float4 ex0 = *reinterpret_cast<const float4*>(&row[tx * 8]);
            float4 ex1 = *reinterpret_cast<const float4*>(&row[tx * 8 + 4]);
            float4 ey0 = *reinterpret_cast<const float4*>(&row[64 + ty * 8]);
            float4 ey1 = *reinterpret_cast<const float4*>(&row[64 + ty * 8 + 4]);
            float ex[8] = {ex0.x, ex0.y, ex0.z, ex0.w, ex1.x, ex1.y, ex1.z, ex1.w};
            float ey[8] = {ey0.x, ey0.y, ey0.z, ey0.w, ey1.x, ey1.y, ey1.z, ey1.w};
#pragma unroll
            for (int i = 0; i < 8; ++i)
#pragma unroll
                for (int j = 0; j < 8; ++j)
                    acc[i][j] = fmaf(ex[i], ey[j], acc[i][j]);
        }
    }

    // ---- phase 2: cross-wave reduction in LDS -> one block partial ----
    __syncthreads();                // all es reads done; safe to alias as gA
    float* gw = (w & 2) ? gB : gA;  // waves 0,1 -> gA; waves 2,3 -> gB
    if (!(w & 1)) {                 // pass 1: waves 0,2 write
#pragma unroll
        for (int i = 0; i < 8; ++i) {
            int base = (tx * 8 + i) * 64 + ty * 8;
            *reinterpret_cast<float4*>(&gw[base]) =
                make_float4(acc[i][0], acc[i][1], acc[i][2], acc[i][3]);
            *reinterpret_cast<float4*>(&gw[base + 4]) =
                make_float4(acc[i][4], acc[i][5], acc[i][6], acc[i][7]);
        }
    }
    __syncthreads();
    if (w & 1) {                    // pass 2: waves 1,3 read-modify-write
#pragma unroll
        for (int i = 0; i < 8; ++i) {
            int base = (tx * 8 + i) * 64 + ty * 8;
            float4 a = *reinterpret_cast<const float4*>(&gw[base]);
            float4 h = *reinterpret_cast<const float4*>(&gw[base + 4]);
            a.x += acc[i][0]; a.y += acc[i][1]; a.z += acc[i][2]; a.w += acc[i][3];
            h.x += acc[i][4]; h.y += acc[i][5]; h.z += acc[i][6]; h.w += acc[i][7];
            *reinterpret_cast<float4*>(&gw[base])     = a;
            *reinterpret_cast<float4*>(&gw[base + 4]) = h;
        }
    }
    __syncthreads();
    // pass 3: all 256 threads sum gA+gB in coalesced float4s, store + total
    float* dst = partials + (size_t)blockIdx.x * NCELL;
    float tsum = 0.f;
#pragma unroll
    for (int q = 0; q < 4; ++q) {
        int f = q * 256 + tid;      // float4 index; lane-consecutive
        float4 a = reinterpret_cast<const float4*>(gA)[f];
        float4 bb = reinterpret_cast<const float4*>(gB)[f];
        float4 r = make_float4(a.x + bb.x, a.y + bb.y, a.z + bb.z, a.w + bb.w);
        reinterpret_cast<float4*>(dst)[f] = r;
        tsum += (r.x + r.y) + (r.z + r.w);
    }
    for (int off = 32; off; off >>= 1) tsum += __shfl_down(tsum, off);
    if (lane == 0) red[w][0] = tsum;
    __syncthreads();
    if (tid == 0)
        totpart[blockIdx.x] = (red[0][0] + red[1][0]) + (red[2][0] + red[3][0]);
}

// ---------------------------------------------------------------------------
// Kernel B: sum 64 block-partials/batch, batch total from totpart,
// scale + normalize. Grid = BATCH*32 = 256 blocks x 128 threads (1 cell/thr).
// ---------------------------------------------------------------------------
__global__ __launch_bounds__(128) void finish_kernel(const float* __restrict__ partials,
                                                     const float* __restrict__ totpart,
                                                     const float* __restrict__ params,
                                                     float* __restrict__ out) {
    const int b     = blockIdx.x >> 5;
    const int strip = blockIdx.x & 31;
    const int cell  = strip * 128 + threadIdx.x;
    const float* p  = partials + (size_t)b * SPLITS * NCELL + cell;

    float s[8] = {0.f, 0.f, 0.f, 0.f, 0.f, 0.f, 0.f, 0.f};
#pragma unroll
    for (int k8 = 0; k8 < 8; ++k8)              // 8 independent chains
#pragma unroll
        for (int j = 0; j < 8; ++j)
            s[j] += p[(size_t)(k8 * 8 + j) * NCELL];
    float sum = ((s[0] + s[1]) + (s[2] + s[3])) + ((s[4] + s[5]) + (s[6] + s[7]));

    __shared__ float tot_s;
    if (threadIdx.x < 64) {
        float v = totpart[b * SPLITS + threadIdx.x];
        for (int off = 32; off; off >>= 1) v += __shfl_down(v, off);
        if (threadIdx.x == 0) tot_s = v;
    }
    __syncthreads();

    const float scale = params[b];
    const float denom = fmaxf(tot_s * scale, 1e-5f);
    out[b * NCELL + cell] = (sum * scale) / denom;
}

// ---------------------------------------------------------------------------
extern "C" void kernel_launch(void* const* d_in, const int* in_sizes, int n_in,
                              void* d_out, int out_size, void* d_ws, size_t ws_size,
                              hipStream_t stream) {
    const float* T = (const float*)d_in[0];   // [B, NV, 2] f32
    // d_in[1] (S) is a deterministic 64x64 meshgrid in [0,1]^2 — derived inline.

    float* ws       = (float*)d_ws;
    float* totpart  = ws + TOTPART_OFF;
    float* params   = ws + PARAMS_OFF;
    float* partials = ws + PARTIALS_OFF;

    kde_kernel<<<BATCH * SPLITS, 256, 0, stream>>>(T, params, totpart, partials);
    finish_kernel<<<BATCH * 32, 128, 0, stream>>>(partials, totpart, params,
                                                  (float*)d_out);
}